// Round 1
// 1676.924 us; speedup vs baseline: 1.2629x; 1.2629x over previous
//
#include <hip/hip_runtime.h>
#include <math.h>

static constexpr int CH   = 112;
static constexpr int HID  = 448;
static constexpr int NPOS = 64 * 64 * 64;            // 262144 = 2^18
static constexpr long long NELEM = (long long)CH * NPOS; // 29360128

typedef _Float16 f16x8 __attribute__((ext_vector_type(8)));
typedef _Float16 f16x4 __attribute__((ext_vector_type(4)));
typedef float    f32x4 __attribute__((ext_vector_type(4)));

__device__ __forceinline__ float gelu_f(float x) {
    return 0.5f * x * (1.0f + erff(x * 0.70710678118654752f));
}

// mean / inv-std from accumulated (sum, sumsq)
__device__ __forceinline__ void stats_from(const double* __restrict__ S, float* mu, float* inv) {
    double m = S[0] / (double)NELEM;
    double v = S[1] / (double)NELEM - m * m;
    *mu  = (float)m;
    *inv = (float)(1.0 / sqrt(v + 1e-5));
}

// block-wide (sum, sumsq) reduction -> atomicAdd into out[0], out[1]
__device__ __forceinline__ void block_reduce2(double s, double q, double* __restrict__ out) {
    #pragma unroll
    for (int off = 32; off > 0; off >>= 1) {
        s += __shfl_down(s, off, 64);
        q += __shfl_down(q, off, 64);
    }
    __shared__ double red[16];
    int lane = threadIdx.x & 63, wv = threadIdx.x >> 6;
    int nw = blockDim.x >> 6;
    if (lane == 0) { red[wv] = s; red[wv + 8] = q; }
    __syncthreads();
    if (threadIdx.x == 0) {
        double S = 0, Q = 0;
        for (int i = 0; i < nw; i++) { S += red[i]; Q += red[i + 8]; }
        atomicAdd(out, S);
        atomicAdd(out + 1, Q);
    }
}

// ---- K1: reduce x -> S0 ----
__global__ void k_reduce(const float* __restrict__ x, double* __restrict__ S) {
    long long i0 = (long long)blockIdx.x * blockDim.x + threadIdx.x;
    long long stride = (long long)gridDim.x * blockDim.x;
    const float4* x4 = (const float4*)x;
    long long n4 = NELEM / 4;
    double s = 0, q = 0;
    for (long long i = i0; i < n4; i += stride) {
        float4 v = x4[i];
        s += (double)v.x + (double)v.y + (double)v.z + (double)v.w;
        q += (double)v.x * v.x + (double)v.y * v.y + (double)v.z * v.z + (double)v.w * v.w;
    }
    block_reduce2(s, q, S);
}

// ---- generic fold: gn(stats,g,bta) into conv weights; writes transposed w'[c][o], b'[o]
__global__ void k_fold(const double* __restrict__ S, const float* __restrict__ w,
                       const float* __restrict__ b, const float* __restrict__ g,
                       const float* __restrict__ bta,
                       float* __restrict__ wt, float* __restrict__ beff) {
    int o = blockIdx.x;
    float mu, inv; stats_from(S, &mu, &inv);
    float partial = 0.f;
    for (int c = threadIdx.x; c < CH; c += blockDim.x) {
        float sc = inv * g[c];
        float sh = bta[c] - mu * sc;
        float wv = w[o * CH + c];
        wt[c * CH + o] = wv * sc;
        partial += wv * sh;
    }
    #pragma unroll
    for (int off = 32; off > 0; off >>= 1) partial += __shfl_down(partial, off, 64);
    __shared__ float rp[2];
    int lane = threadIdx.x & 63, wv_ = threadIdx.x >> 6;
    if (lane == 0) rp[wv_] = partial;
    __syncthreads();
    if (threadIdx.x == 0) beff[o] = b[o] + rp[0] + rp[1];
}

// ---- fold n2 gn into fc1, write f16 MFMA-A layout fc1h[h][128] (K zero-padded), b1m[h]
__global__ void k_fold_fc1(const double* __restrict__ S, const float* __restrict__ fw,
                           const float* __restrict__ fb, const float* __restrict__ g,
                           const float* __restrict__ bta,
                           _Float16* __restrict__ fc1h, float* __restrict__ b1m) {
    int h = blockIdx.x;
    float mu, inv; stats_from(S, &mu, &inv);
    float partial = 0.f;
    for (int c = threadIdx.x; c < 128; c += blockDim.x) {
        float w_ = 0.f, contrib = 0.f;
        if (c < CH) {
            float sc = inv * g[c];
            float sh = bta[c] - mu * sc;
            float wv = fw[h * CH + c];
            w_ = wv * sc;
            contrib = wv * sh;
        }
        fc1h[h * 128 + c] = (_Float16)w_;
        partial += contrib;
    }
    #pragma unroll
    for (int off = 32; off > 0; off >>= 1) partial += __shfl_down(partial, off, 64);
    __shared__ float rp[2];
    int lane = threadIdx.x & 63, wv_ = threadIdx.x >> 6;
    if (lane == 0) rp[wv_] = partial;
    __syncthreads();
    if (threadIdx.x == 0) b1m[h] = fb[h] + rp[0] + rp[1];
}

// ---- transposes (no stats deps): w2{d,h,w}t[c][o]; fc2 weights cast to f16 (same layout)
__global__ void k_transpose(const float* __restrict__ w2d, const float* __restrict__ w2h,
                            const float* __restrict__ w2w, const float* __restrict__ fc2w,
                            float* __restrict__ w2dt, float* __restrict__ w2ht,
                            float* __restrict__ w2wt, _Float16* __restrict__ fc2h) {
    int b = blockIdx.x;
    if (b < CH) {
        for (int c = threadIdx.x; c < CH; c += blockDim.x) {
            w2dt[c * CH + b] = w2d[b * CH + c];
            w2ht[c * CH + b] = w2h[b * CH + c];
            w2wt[c * CH + b] = w2w[b * CH + c];
        }
    }
    // elementwise cast of fc2w (112x448 row-major): 448 blocks x 112 elems
    for (int i = threadIdx.x; i < CH; i += blockDim.x) {
        fc2h[b * CH + i] = (_Float16)fc2w[b * CH + i];
    }
}

// ---- K3: t = conv1'(x) (gn folded), + stats of t -> S1 ----
__global__ void __launch_bounds__(256)
k_conv1(const float* __restrict__ x, const float* __restrict__ w1t,
        const float* __restrict__ b1e, float* __restrict__ t, double* __restrict__ S1) {
    __shared__ float lx[CH][64];
    int lane = threadIdx.x & 63;
    int wv = __builtin_amdgcn_readfirstlane(threadIdx.x >> 6);
    int pos0 = blockIdx.x * 64;
    int ob = wv * 28;

    // stage tile
    {
        int c0 = threadIdx.x >> 4;         // 0..15
        int q  = threadIdx.x & 15;         // float4 idx within row
        #pragma unroll
        for (int p = 0; p < 7; p++) {
            int c = p * 16 + c0;
            float4 v = *(const float4*)(x + (long long)c * NPOS + pos0 + q * 4);
            *(float4*)(&lx[c][q * 4]) = v;
        }
    }
    __syncthreads();

    float acc[28];
    #pragma unroll
    for (int j = 0; j < 28; j++) acc[j] = 0.f;
    #pragma unroll 4
    for (int c = 0; c < CH; c++) {
        float v = lx[c][lane];
        const float* wr = w1t + c * CH + ob;
        #pragma unroll
        for (int j = 0; j < 28; j++) acc[j] += wr[j] * v;
    }
    double s = 0, q = 0;
    #pragma unroll
    for (int j = 0; j < 28; j++) {
        float tv = acc[j] + b1e[ob + j];
        t[(ob + j) * NPOS + pos0 + lane] = tv;
        s += (double)tv; q += (double)tv * tv;
    }
    block_reduce2(s, q, S1);
}

// ---- K5: a = gelu(gn_affine(t)) in place ----
__global__ void k_act(float* __restrict__ t, const double* __restrict__ S1,
                      const float* __restrict__ g, const float* __restrict__ bta) {
    float mu, inv; stats_from(S1, &mu, &inv);
    int i4 = blockIdx.x * blockDim.x + threadIdx.x;   // float4 index; NELEM/4 total
    int c = i4 >> 16;                                  // 65536 float4 per channel
    float sc = inv * g[c], sh = bta[c] - mu * sc;
    float4* t4 = (float4*)t;
    float4 v = t4[i4];
    v.x = gelu_f(v.x * sc + sh);
    v.y = gelu_f(v.y * sc + sh);
    v.z = gelu_f(v.z * sc + sh);
    v.w = gelu_f(v.w * sc + sh);
    t4[i4] = v;
}

// ---- K6: s = sum of 3 shifted-conv-gelu branches, + stats -> S2 ----
__global__ void __launch_bounds__(256)
k_shift(const float* __restrict__ a,
        const float* __restrict__ w2dt, const float* __restrict__ b2d,
        const float* __restrict__ w2ht, const float* __restrict__ b2h,
        const float* __restrict__ w2wt, const float* __restrict__ b2w,
        float* __restrict__ sout, double* __restrict__ S2) {
    __shared__ float ls[CH][64];
    int lane = threadIdx.x & 63;
    int wv = __builtin_amdgcn_readfirstlane(threadIdx.x >> 6);
    int d = blockIdx.x >> 6, h = blockIdx.x & 63;
    int ob = wv * 28;
    int c0 = threadIdx.x >> 4;         // loader: channel sub-index 0..15
    int qq = threadIdx.x & 15;         // loader: float4 within row

    float tot[28];
    #pragma unroll
    for (int j = 0; j < 28; j++) tot[j] = 0.f;
    float acc[28];

    // ================= branch D: a[c, d - s_c, h, lane] =================
    #pragma unroll
    for (int p = 0; p < 7; p++) {
        int c = p * 16 + c0;
        int sft = (c >> 4) - 3;
        int dd = d - sft;
        float4 v = make_float4(0.f, 0.f, 0.f, 0.f);
        if ((unsigned)dd < 64u)
            v = *(const float4*)(a + (long long)c * NPOS + dd * 4096 + h * 64 + qq * 4);
        *(float4*)(&ls[c][qq * 4]) = v;
    }
    __syncthreads();
    #pragma unroll
    for (int j = 0; j < 28; j++) acc[j] = 0.f;
    #pragma unroll 4
    for (int c = 0; c < CH; c++) {
        float v = ls[c][lane];
        const float* wr = w2dt + c * CH + ob;
        #pragma unroll
        for (int j = 0; j < 28; j++) acc[j] += wr[j] * v;
    }
    #pragma unroll
    for (int j = 0; j < 28; j++) tot[j] += gelu_f(acc[j] + b2d[ob + j]);
    __syncthreads();

    // ================= branch H: a[c, d-3, h-3-s_c, lane-3] =================
    {
        int dd = d - 3;
        bool dok = (unsigned)dd < 64u;
        #pragma unroll
        for (int p = 0; p < 7; p++) {
            int c = p * 16 + c0;
            int sft = (c >> 4) - 3;
            int hh = h - 3 - sft;
            float4 v = make_float4(0.f, 0.f, 0.f, 0.f);
            if (dok && (unsigned)hh < 64u)
                v = *(const float4*)(a + (long long)c * NPOS + dd * 4096 + hh * 64 + qq * 4);
            *(float4*)(&ls[c][qq * 4]) = v;
        }
    }
    __syncthreads();
    #pragma unroll
    for (int j = 0; j < 28; j++) acc[j] = 0.f;
    {
        int wi = lane - 3;
        bool wok = wi >= 0;
        #pragma unroll 4
        for (int c = 0; c < CH; c++) {
            float v = wok ? ls[c][wi & 63] : 0.f;
            const float* wr = w2ht + c * CH + ob;
            #pragma unroll
            for (int j = 0; j < 28; j++) acc[j] += wr[j] * v;
        }
    }
    #pragma unroll
    for (int j = 0; j < 28; j++) tot[j] += gelu_f(acc[j] + b2h[ob + j]);
    __syncthreads();

    // ================= branch W: a[c, d-6, h-6, lane-6-s_c] =================
    {
        int dd = d - 6, hh = h - 6;
        bool ok = ((unsigned)dd < 64u) && ((unsigned)hh < 64u);
        #pragma unroll
        for (int p = 0; p < 7; p++) {
            int c = p * 16 + c0;
            float4 v = make_float4(0.f, 0.f, 0.f, 0.f);
            if (ok)
                v = *(const float4*)(a + (long long)c * NPOS + dd * 4096 + hh * 64 + qq * 4);
            *(float4*)(&ls[c][qq * 4]) = v;
        }
    }
    __syncthreads();
    #pragma unroll
    for (int j = 0; j < 28; j++) acc[j] = 0.f;
    #pragma unroll 4
    for (int c = 0; c < CH; c++) {
        int sft = (c >> 4) - 3;
        int wi = lane - 6 - sft;
        float v = ((unsigned)wi < 64u) ? ls[c][wi & 63] : 0.f;
        const float* wr = w2wt + c * CH + ob;
        #pragma unroll
        for (int j = 0; j < 28; j++) acc[j] += wr[j] * v;
    }
    #pragma unroll
    for (int j = 0; j < 28; j++) tot[j] += gelu_f(acc[j] + b2w[ob + j]);

    int pos = d * 4096 + h * 64 + lane;
    double s = 0, q = 0;
    #pragma unroll
    for (int j = 0; j < 28; j++) {
        float sv = tot[j];
        sout[(ob + j) * NPOS + pos] = sv;
        s += (double)sv; q += (double)sv * sv;
    }
    block_reduce2(s, q, S2);
}

// ---- K8: x1 = x + conv3'(s) + h0(x), + stats -> S3 ----
__global__ void __launch_bounds__(256)
k_comb(const float* __restrict__ sbuf, const float* __restrict__ x,
       const float* __restrict__ w3t, const float* __restrict__ b3e,
       const double* __restrict__ S0, const float* __restrict__ n1g,
       const float* __restrict__ n1b, float* __restrict__ x1, double* __restrict__ S3) {
    __shared__ float ls[CH][64];
    int lane = threadIdx.x & 63;
    int wv = __builtin_amdgcn_readfirstlane(threadIdx.x >> 6);
    int pos0 = blockIdx.x * 64;
    int ob = wv * 28;

    {
        int c0 = threadIdx.x >> 4;
        int qq = threadIdx.x & 15;
        #pragma unroll
        for (int p = 0; p < 7; p++) {
            int c = p * 16 + c0;
            float4 v = *(const float4*)(sbuf + (long long)c * NPOS + pos0 + qq * 4);
            *(float4*)(&ls[c][qq * 4]) = v;
        }
    }
    __syncthreads();

    float acc[28];
    #pragma unroll
    for (int j = 0; j < 28; j++) acc[j] = 0.f;
    #pragma unroll 4
    for (int c = 0; c < CH; c++) {
        float v = ls[c][lane];
        const float* wr = w3t + c * CH + ob;
        #pragma unroll
        for (int j = 0; j < 28; j++) acc[j] += wr[j] * v;
    }
    float mu, inv; stats_from(S0, &mu, &inv);
    double s = 0, q = 0;
    #pragma unroll
    for (int j = 0; j < 28; j++) {
        int o = ob + j;
        float y  = acc[j] + b3e[o];
        float xv = x[(long long)o * NPOS + pos0 + lane];
        float sc = inv * n1g[o];
        float h0 = xv * sc + (n1b[o] - mu * sc);
        float v  = xv + y + h0;
        x1[(long long)o * NPOS + pos0 + lane] = v;
        s += (double)v; q += (double)v * v;
    }
    block_reduce2(s, q, S3);
}

// ---- K10: out = x1 + fc2(gelu(fc1'(x1))), via f16 MFMA, in place on x1 buffer ----
// Per block: 64 positions. Stage0: x1 tile -> lxT[pos][c] f16 (transposed, K-contig).
// Stage1: 4 waves split HID (112 rows each): H = fc1h * X (7m x 4n x 4k MFMAs),
//         gelu in f32 -> GT[pos][hid] f16.
// Stage2: 4 waves split pos (16 each): M = fc2h * G (7m x 14k MFMAs),
//         epilogue re-reads x1 in f32 for exact residual.
__global__ void __launch_bounds__(256, 2)
k_mlp(float* __restrict__ x1out, const _Float16* __restrict__ fc1h,
      const float* __restrict__ b1m, const _Float16* __restrict__ fc2h,
      const float* __restrict__ fc2b) {
    // pitches padded (136, 456 halves) so fragment ds_read_b128 is ~2-way conflict free
    __shared__ __align__(16) _Float16 lxT[64][136];
    __shared__ __align__(16) _Float16 GT[64][456];
    int tid  = threadIdx.x;
    int lane = tid & 63;
    int wv   = tid >> 6;
    int l15  = lane & 15;
    int l4   = lane >> 4;            // 0..3
    int pos0 = blockIdx.x * 64;

    // ---- stage 0: load + transpose + f16-convert x1 tile ----
    {
        int c0 = tid >> 4;           // 0..15
        int q  = tid & 15;           // float4 group within row
        #pragma unroll
        for (int p = 0; p < 7; p++) {
            int c = p * 16 + c0;
            float4 v = *(const float4*)(x1out + (long long)c * NPOS + pos0 + q * 4);
            lxT[q * 4 + 0][c] = (_Float16)v.x;
            lxT[q * 4 + 1][c] = (_Float16)v.y;
            lxT[q * 4 + 2][c] = (_Float16)v.z;
            lxT[q * 4 + 3][c] = (_Float16)v.w;
        }
        // zero K-pad c = 112..127 (read by k-step 3)
        for (int i = tid; i < 64 * 16; i += 256) {
            lxT[i >> 4][112 + (i & 15)] = (_Float16)0.f;
        }
    }
    __syncthreads();

    // ---- stage 1: H = fc1h(448x128) * X(128x64); this wave: hid rows [hb, hb+112) ----
    int hb = wv * 112;
    f32x4 acc1[7][4];
    {
        f32x4 z = {0.f, 0.f, 0.f, 0.f};
        #pragma unroll
        for (int mt = 0; mt < 7; mt++)
            #pragma unroll
            for (int nt = 0; nt < 4; nt++) acc1[mt][nt] = z;
    }
    #pragma unroll
    for (int kk = 0; kk < 4; kk++) {
        f16x8 a[7];
        #pragma unroll
        for (int mt = 0; mt < 7; mt++)
            a[mt] = *(const f16x8*)(fc1h + (hb + mt * 16 + l15) * 128 + kk * 32 + l4 * 8);
        #pragma unroll
        for (int nt = 0; nt < 4; nt++) {
            f16x8 b = *(const f16x8*)(&lxT[nt * 16 + l15][kk * 32 + l4 * 8]);
            #pragma unroll
            for (int mt = 0; mt < 7; mt++)
                acc1[mt][nt] = __builtin_amdgcn_mfma_f32_16x16x32_f16(a[mt], b, acc1[mt][nt], 0, 0, 0);
        }
    }
    // bias + gelu (f32) -> GT (f16); D layout: row = 4*l4+r (hid), col = l15 (pos)
    #pragma unroll
    for (int mt = 0; mt < 7; mt++) {
        int hbase = hb + mt * 16 + l4 * 4;
        float4 bias = *(const float4*)(b1m + hbase);
        #pragma unroll
        for (int nt = 0; nt < 4; nt++) {
            f16x4 g4;
            g4[0] = (_Float16)gelu_f(acc1[mt][nt][0] + bias.x);
            g4[1] = (_Float16)gelu_f(acc1[mt][nt][1] + bias.y);
            g4[2] = (_Float16)gelu_f(acc1[mt][nt][2] + bias.z);
            g4[3] = (_Float16)gelu_f(acc1[mt][nt][3] + bias.w);
            *(f16x4*)(&GT[nt * 16 + l15][hbase]) = g4;
        }
    }
    __syncthreads();

    // ---- stage 2: M = fc2h(112x448) * G(448x16); this wave: pos [wv*16, wv*16+16) ----
    int pw = wv * 16 + l15;
    f32x4 acc2[7];
    {
        f32x4 z = {0.f, 0.f, 0.f, 0.f};
        #pragma unroll
        for (int mt = 0; mt < 7; mt++) acc2[mt] = z;
    }
    #pragma unroll 2
    for (int kk = 0; kk < 14; kk++) {
        f16x8 b = *(const f16x8*)(&GT[pw][kk * 32 + l4 * 8]);
        #pragma unroll
        for (int mt = 0; mt < 7; mt++) {
            f16x8 a = *(const f16x8*)(fc2h + (mt * 16 + l15) * 448 + kk * 32 + l4 * 8);
            acc2[mt] = __builtin_amdgcn_mfma_f32_16x16x32_f16(a, b, acc2[mt], 0, 0, 0);
        }
    }
    // epilogue: exact f32 residual re-read
    long long gp = pos0 + pw;
    #pragma unroll
    for (int mt = 0; mt < 7; mt++) {
        int ob = mt * 16 + l4 * 4;
        float4 b2 = *(const float4*)(fc2b + ob);
        float bb[4] = {b2.x, b2.y, b2.z, b2.w};
        #pragma unroll
        for (int r = 0; r < 4; r++) {
            long long idx = (long long)(ob + r) * NPOS + gp;
            x1out[idx] = x1out[idx] + acc2[mt][r] + bb[r];
        }
    }
}

extern "C" void kernel_launch(void* const* d_in, const int* in_sizes, int n_in,
                              void* d_out, int out_size, void* d_ws, size_t ws_size,
                              hipStream_t stream) {
    const float* x       = (const float*)d_in[0];
    const float* conv1_w = (const float*)d_in[1];
    const float* conv1_b = (const float*)d_in[2];
    const float* conv2d_w= (const float*)d_in[3];
    const float* conv2d_b= (const float*)d_in[4];
    const float* conv2h_w= (const float*)d_in[5];
    const float* conv2h_b= (const float*)d_in[6];
    const float* conv2w_w= (const float*)d_in[7];
    const float* conv2w_b= (const float*)d_in[8];
    const float* conv3_w = (const float*)d_in[9];
    const float* conv3_b = (const float*)d_in[10];
    const float* fc1_w   = (const float*)d_in[11];
    const float* fc1_b   = (const float*)d_in[12];
    const float* fc2_w   = (const float*)d_in[13];
    const float* fc2_b   = (const float*)d_in[14];
    const float* n1_g    = (const float*)d_in[15];
    const float* n1_b    = (const float*)d_in[16];
    const float* na1_g   = (const float*)d_in[17];
    const float* na1_b   = (const float*)d_in[18];
    const float* na2_g   = (const float*)d_in[19];
    const float* na2_b   = (const float*)d_in[20];
    const float* n2_g    = (const float*)d_in[21];
    const float* n2_b    = (const float*)d_in[22];

    char* ws = (char*)d_ws;
    double* S = (double*)ws;                 // S0=S, S1=S+2, S2=S+4, S3=S+6
    float* prm  = (float*)(ws + 512);
    float* w1t  = prm;              // 12544
    float* b1e  = w1t  + 12544;     // 112
    float* w2dt = b1e  + 112;       // 12544
    float* w2ht = w2dt + 12544;     // 12544
    float* w2wt = w2ht + 12544;     // 12544
    float* w3t  = w2wt + 12544;     // 12544
    float* b3e  = w3t  + 12544;     // 112
    float* b1m  = b3e  + 112;       // 448
    _Float16* fc1h = (_Float16*)(b1m + 448); // 448*128 f16 = 114688 B (16B aligned)
    _Float16* fc2h = fc1h + 448 * 128;       // 112*448 f16 = 100352 B
    float* bufA = (float*)(ws + (1 << 20));  // 117,440,512 B
    float* out  = (float*)d_out;             // doubles as second big buffer

    hipMemsetAsync(S, 0, 8 * sizeof(double), stream);
    k_transpose<<<448, 128, 0, stream>>>(conv2d_w, conv2h_w, conv2w_w, fc2_w,
                                         w2dt, w2ht, w2wt, fc2h);
    k_reduce<<<1024, 256, 0, stream>>>(x, S);
    k_fold<<<112, 128, 0, stream>>>(S, conv1_w, conv1_b, n1_g, n1_b, w1t, b1e);
    k_conv1<<<4096, 256, 0, stream>>>(x, w1t, b1e, out, S + 2);
    k_act<<<28672, 256, 0, stream>>>(out, S + 2, na1_g, na1_b);
    k_shift<<<4096, 256, 0, stream>>>(out, w2dt, conv2d_b, w2ht, conv2h_b,
                                      w2wt, conv2w_b, bufA, S + 4);
    k_fold<<<112, 128, 0, stream>>>(S + 4, conv3_w, conv3_b, na2_g, na2_b, w3t, b3e);
    k_comb<<<4096, 256, 0, stream>>>(bufA, x, w3t, b3e, S, n1_g, n1_b, out, S + 6);
    k_fold_fc1<<<448, 128, 0, stream>>>(S + 6, fc1_w, fc1_b, n2_g, n2_b, fc1h, b1m);
    k_mlp<<<4096, 256, 0, stream>>>(out, fc1h, b1m, fc2h, fc2_b);
}

// Round 2
// 1201.455 us; speedup vs baseline: 1.7627x; 1.3957x over previous
//
#include <hip/hip_runtime.h>
#include <math.h>

static constexpr int CH   = 112;
static constexpr int HID  = 448;
static constexpr int NPOS = 64 * 64 * 64;            // 262144 = 2^18
static constexpr long long NELEM = (long long)CH * NPOS; // 29360128

typedef _Float16 f16x8 __attribute__((ext_vector_type(8)));
typedef _Float16 f16x4 __attribute__((ext_vector_type(4)));
typedef float    f32x4 __attribute__((ext_vector_type(4)));

__device__ __forceinline__ float gelu_f(float x) {
    return 0.5f * x * (1.0f + erff(x * 0.70710678118654752f));
}

__device__ __forceinline__ void stats_from(const double* __restrict__ S, float* mu, float* inv) {
    double m = S[0] / (double)NELEM;
    double v = S[1] / (double)NELEM - m * m;
    *mu  = (float)m;
    *inv = (float)(1.0 / sqrt(v + 1e-5));
}

__device__ __forceinline__ void block_reduce2(double s, double q, double* __restrict__ out) {
    #pragma unroll
    for (int off = 32; off > 0; off >>= 1) {
        s += __shfl_down(s, off, 64);
        q += __shfl_down(q, off, 64);
    }
    __shared__ double red[16];
    int lane = threadIdx.x & 63, wv = threadIdx.x >> 6;
    int nw = blockDim.x >> 6;
    if (lane == 0) { red[wv] = s; red[wv + 8] = q; }
    __syncthreads();
    if (threadIdx.x == 0) {
        double S = 0, Q = 0;
        for (int i = 0; i < nw; i++) { S += red[i]; Q += red[i + 8]; }
        atomicAdd(out, S);
        atomicAdd(out + 1, Q);
    }
}

// 7m x 1n(per-wave) x 4k MFMA tile: A = w[o][128] f16, B = lsT[pos][c]
__device__ __forceinline__ void mfma_tile(const _Float16* __restrict__ w,
                                          const _Float16 (*lsT)[136],
                                          int l15, int l4, int wv, f32x4 acc[7]) {
    #pragma unroll
    for (int kk = 0; kk < 4; kk++) {
        f16x8 b = *(const f16x8*)(&lsT[wv * 16 + l15][kk * 32 + l4 * 8]);
        #pragma unroll
        for (int mt = 0; mt < 7; mt++) {
            f16x8 a = *(const f16x8*)(w + (mt * 16 + l15) * 128 + kk * 32 + l4 * 8);
            acc[mt] = __builtin_amdgcn_mfma_f32_16x16x32_f16(a, b, acc[mt], 0, 0, 0);
        }
    }
}

__device__ __forceinline__ void accum_gelu(f32x4 tot[7], const f32x4 acc[7],
                                           const float* __restrict__ b, int l4) {
    #pragma unroll
    for (int mt = 0; mt < 7; mt++) {
        float4 bb = *(const float4*)(b + mt * 16 + l4 * 4);
        tot[mt][0] += gelu_f(acc[mt][0] + bb.x);
        tot[mt][1] += gelu_f(acc[mt][1] + bb.y);
        tot[mt][2] += gelu_f(acc[mt][2] + bb.z);
        tot[mt][3] += gelu_f(acc[mt][3] + bb.w);
    }
}

// ---- K1: reduce x -> S0 ----
__global__ void k_reduce(const float* __restrict__ x, double* __restrict__ S) {
    long long i0 = (long long)blockIdx.x * blockDim.x + threadIdx.x;
    long long stride = (long long)gridDim.x * blockDim.x;
    const float4* x4 = (const float4*)x;
    long long n4 = NELEM / 4;
    double s = 0, q = 0;
    for (long long i = i0; i < n4; i += stride) {
        float4 v = x4[i];
        s += (double)v.x + (double)v.y + (double)v.z + (double)v.w;
        q += (double)v.x * v.x + (double)v.y * v.y + (double)v.z * v.z + (double)v.w * v.w;
    }
    block_reduce2(s, q, S);
}

// ---- generic fold: gn(stats,g,bta) into conv/fc weights; writes f16 [o][128] K-padded, beff[o]
//      works for conv1 (112 rows), conv3 (112 rows), fc1 (448 rows) — all have K=CH=112.
__global__ void k_fold(const double* __restrict__ S, const float* __restrict__ w,
                       const float* __restrict__ b, const float* __restrict__ g,
                       const float* __restrict__ bta,
                       _Float16* __restrict__ w16, float* __restrict__ beff) {
    int o = blockIdx.x;
    float mu, inv; stats_from(S, &mu, &inv);
    float partial = 0.f;
    for (int c = threadIdx.x; c < 128; c += blockDim.x) {
        float wv_ = 0.f, contrib = 0.f;
        if (c < CH) {
            float sc = inv * g[c];
            float sh = bta[c] - mu * sc;
            float w0 = w[o * CH + c];
            wv_ = w0 * sc;
            contrib = w0 * sh;
        }
        w16[o * 128 + c] = (_Float16)wv_;
        partial += contrib;
    }
    #pragma unroll
    for (int off = 32; off > 0; off >>= 1) partial += __shfl_down(partial, off, 64);
    __shared__ float rp[2];
    int lane = threadIdx.x & 63, wv_ = threadIdx.x >> 6;
    if (lane == 0) rp[wv_] = partial;
    __syncthreads();
    if (threadIdx.x == 0) beff[o] = b[o] + rp[0] + rp[1];
}

// ---- casts (no stats deps): w2{d,h,w} -> f16 [o][128] K-padded; fc2 -> f16 same layout
__global__ void k_cast(const float* __restrict__ w2d, const float* __restrict__ w2h,
                       const float* __restrict__ w2w, const float* __restrict__ fc2w,
                       _Float16* __restrict__ w2dh, _Float16* __restrict__ w2hh,
                       _Float16* __restrict__ w2wh, _Float16* __restrict__ fc2h) {
    int b = blockIdx.x;
    if (b < CH) {
        for (int c = threadIdx.x; c < 128; c += blockDim.x) {
            float vd = 0.f, vh = 0.f, vw = 0.f;
            if (c < CH) { vd = w2d[b * CH + c]; vh = w2h[b * CH + c]; vw = w2w[b * CH + c]; }
            w2dh[b * 128 + c] = (_Float16)vd;
            w2hh[b * 128 + c] = (_Float16)vh;
            w2wh[b * 128 + c] = (_Float16)vw;
        }
    }
    for (int i = threadIdx.x; i < CH; i += blockDim.x)
        fc2h[b * CH + i] = (_Float16)fc2w[b * CH + i];
}

// ---- K3: t16[pos][128] = conv1'(x) (gn folded) f16, + stats of t (pre-round f32) -> S1 ----
__global__ void __launch_bounds__(256, 2)
k_conv1(const float* __restrict__ x, const _Float16* __restrict__ w1h,
        const float* __restrict__ b1e, _Float16* __restrict__ t16, double* __restrict__ S1) {
    __shared__ __align__(16) _Float16 lxT[64][136];
    int tid = threadIdx.x, lane = tid & 63, wv = tid >> 6, l15 = lane & 15, l4 = lane >> 4;
    int pos0 = blockIdx.x * 64;

    // stage: x chan-major f32 -> lxT[pos][c] f16 (transpose)
    {
        int c0 = tid >> 4, q = tid & 15;
        #pragma unroll
        for (int p = 0; p < 7; p++) {
            int c = p * 16 + c0;
            float4 v = *(const float4*)(x + (long long)c * NPOS + pos0 + q * 4);
            lxT[q * 4 + 0][c] = (_Float16)v.x;
            lxT[q * 4 + 1][c] = (_Float16)v.y;
            lxT[q * 4 + 2][c] = (_Float16)v.z;
            lxT[q * 4 + 3][c] = (_Float16)v.w;
        }
        for (int i = tid; i < 64 * 16; i += 256) lxT[i >> 4][112 + (i & 15)] = (_Float16)0.f;
    }
    __syncthreads();

    f32x4 acc[7];
    {
        f32x4 z = {0.f, 0.f, 0.f, 0.f};
        #pragma unroll
        for (int mt = 0; mt < 7; mt++) acc[mt] = z;
    }
    mfma_tile(w1h, lxT, l15, l4, wv, acc);

    long long posw = pos0 + wv * 16 + l15;
    double s = 0, q = 0;
    #pragma unroll
    for (int mt = 0; mt < 7; mt++) {
        int ob = mt * 16 + l4 * 4;
        float4 bb = *(const float4*)(b1e + ob);
        const float* bp = (const float*)&bb;
        f16x4 o4;
        #pragma unroll
        for (int r = 0; r < 4; r++) {
            float tv = acc[mt][r] + bp[r];
            o4[r] = (_Float16)tv;
            s += (double)tv; q += (double)tv * tv;
        }
        *(f16x4*)(t16 + posw * 128 + ob) = o4;
    }
    {   // zero K-pad columns so downstream fragments read zeros
        f16x4 z4; z4[0] = z4[1] = z4[2] = z4[3] = (_Float16)0.f;
        *(f16x4*)(t16 + posw * 128 + 112 + l4 * 4) = z4;
    }
    block_reduce2(s, q, S1);
}

// ---- K5: a16 = gelu(gn_affine(t16)), both [pos][128] f16 ----
__global__ void k_act(const _Float16* __restrict__ t16, _Float16* __restrict__ a16,
                      const double* __restrict__ S1, const float* __restrict__ g,
                      const float* __restrict__ bta) {
    float mu, inv; stats_from(S1, &mu, &inv);
    long long i8 = (long long)blockIdx.x * blockDim.x + threadIdx.x; // f16x8 unit
    int c = (int)((i8 * 8) & 127);
    f16x8 r;
    if (c < 112) {
        f16x8 v = *(const f16x8*)(t16 + i8 * 8);
        float4 g0 = *(const float4*)(g + c);
        float4 g1 = *(const float4*)(g + c + 4);
        float4 b0 = *(const float4*)(bta + c);
        float4 b1 = *(const float4*)(bta + c + 4);
        const float* gp0 = (const float*)&g0; const float* gp1 = (const float*)&g1;
        const float* bp0 = (const float*)&b0; const float* bp1 = (const float*)&b1;
        #pragma unroll
        for (int j = 0; j < 4; j++) {
            float sc = inv * gp0[j], sh = bp0[j] - mu * sc;
            r[j] = (_Float16)gelu_f((float)v[j] * sc + sh);
        }
        #pragma unroll
        for (int j = 0; j < 4; j++) {
            float sc = inv * gp1[j], sh = bp1[j] - mu * sc;
            r[4 + j] = (_Float16)gelu_f((float)v[4 + j] * sc + sh);
        }
    } else {
        #pragma unroll
        for (int j = 0; j < 8; j++) r[j] = (_Float16)0.f;
    }
    *(f16x8*)(a16 + i8 * 8) = r;
}

// ---- K6: s16 = sum of 3 shifted-conv-gelu branches (f16 MFMA), + stats -> S2 ----
// a16 layout [pos][128]: per-channel-group shifts resolved as row offsets at staging;
// staging = 4 coalesced f16x8 loads + 4 ds_write_b128 per thread per branch.
__global__ void __launch_bounds__(256, 2)
k_shift(const _Float16* __restrict__ a16,
        const _Float16* __restrict__ w2dh, const float* __restrict__ b2d,
        const _Float16* __restrict__ w2hh, const float* __restrict__ b2h,
        const _Float16* __restrict__ w2wh, const float* __restrict__ b2w,
        _Float16* __restrict__ s16, double* __restrict__ S2) {
    __shared__ __align__(16) _Float16 lsT[64][136];
    int tid = threadIdx.x, lane = tid & 63, wv = tid >> 6, l15 = lane & 15, l4 = lane >> 4;
    int d = blockIdx.x >> 6, h = blockIdx.x & 63;

    f32x4 tot[7], acc[7];
    {
        f32x4 z = {0.f, 0.f, 0.f, 0.f};
        #pragma unroll
        for (int mt = 0; mt < 7; mt++) tot[mt] = z;
    }
    f16x8 z8;
    #pragma unroll
    for (int j = 0; j < 8; j++) z8[j] = (_Float16)0.f;

    // ====== branch D: src = a[c, d - sft_p, h, w] ======
    for (int u = tid; u < 1024; u += 256) {
        int w = u >> 4, u16 = u & 15;
        f16x8 v = z8;
        if (u16 < 14) {
            int p = u16 >> 1;                 // channel group 0..6
            int dd = d - (p - 3);
            if ((unsigned)dd < 64u)
                v = *(const f16x8*)(a16 + (long long)(dd * 4096 + h * 64 + w) * 128 + u16 * 8);
        }
        *(f16x8*)(&lsT[w][u16 * 8]) = v;
    }
    __syncthreads();
    {
        f32x4 z = {0.f, 0.f, 0.f, 0.f};
        #pragma unroll
        for (int mt = 0; mt < 7; mt++) acc[mt] = z;
    }
    mfma_tile(w2dh, lsT, l15, l4, wv, acc);
    accum_gelu(tot, acc, b2d, l4);
    __syncthreads();

    // ====== branch H: src = a[c, d-3, h - p, w-3] ======
    {
        int dd = d - 3;
        bool dok = (unsigned)dd < 64u;
        for (int u = tid; u < 1024; u += 256) {
            int w = u >> 4, u16 = u & 15;
            f16x8 v = z8;
            if (u16 < 14) {
                int p = u16 >> 1;
                int hh = h - p;               // h - 3 - (p-3)
                int ww = w - 3;
                if (dok && (unsigned)hh < 64u && ww >= 0)
                    v = *(const f16x8*)(a16 + (long long)(dd * 4096 + hh * 64 + ww) * 128 + u16 * 8);
            }
            *(f16x8*)(&lsT[w][u16 * 8]) = v;
        }
    }
    __syncthreads();
    {
        f32x4 z = {0.f, 0.f, 0.f, 0.f};
        #pragma unroll
        for (int mt = 0; mt < 7; mt++) acc[mt] = z;
    }
    mfma_tile(w2hh, lsT, l15, l4, wv, acc);
    accum_gelu(tot, acc, b2h, l4);
    __syncthreads();

    // ====== branch W: src = a[c, d-6, h-6, w - 3 - p] ======
    {
        int dd = d - 6, hh = h - 6;
        bool ok = ((unsigned)dd < 64u) && ((unsigned)hh < 64u);
        for (int u = tid; u < 1024; u += 256) {
            int w = u >> 4, u16 = u & 15;
            f16x8 v = z8;
            if (ok && u16 < 14) {
                int p = u16 >> 1;
                int ww = w - 3 - p;           // w - 6 - (p-3)
                if ((unsigned)ww < 64u)
                    v = *(const f16x8*)(a16 + (long long)(dd * 4096 + hh * 64 + ww) * 128 + u16 * 8);
            }
            *(f16x8*)(&lsT[w][u16 * 8]) = v;
        }
    }
    __syncthreads();
    {
        f32x4 z = {0.f, 0.f, 0.f, 0.f};
        #pragma unroll
        for (int mt = 0; mt < 7; mt++) acc[mt] = z;
    }
    mfma_tile(w2wh, lsT, l15, l4, wv, acc);
    accum_gelu(tot, acc, b2w, l4);

    // epilogue: s16 [pos][128] f16, stats from f32
    long long posw = d * 4096 + h * 64 + wv * 16 + l15;
    double s = 0, q = 0;
    #pragma unroll
    for (int mt = 0; mt < 7; mt++) {
        f16x4 o4;
        #pragma unroll
        for (int r = 0; r < 4; r++) {
            float sv = tot[mt][r];
            o4[r] = (_Float16)sv;
            s += (double)sv; q += (double)sv * sv;
        }
        *(f16x4*)(s16 + posw * 128 + mt * 16 + l4 * 4) = o4;
    }
    {
        f16x4 z4; z4[0] = z4[1] = z4[2] = z4[3] = (_Float16)0.f;
        *(f16x4*)(s16 + posw * 128 + 112 + l4 * 4) = z4;
    }
    block_reduce2(s, q, S2);
}

// ---- K8: x1 = x + conv3'(s16) + h0(x), + stats -> S3 ----
__global__ void __launch_bounds__(256, 2)
k_comb(const _Float16* __restrict__ s16, const float* __restrict__ x,
       const _Float16* __restrict__ w3h, const float* __restrict__ b3e,
       const double* __restrict__ S0, const float* __restrict__ n1g,
       const float* __restrict__ n1b, float* __restrict__ x1, double* __restrict__ S3) {
    __shared__ __align__(16) _Float16 lsT[64][136];
    int tid = threadIdx.x, lane = tid & 63, wv = tid >> 6, l15 = lane & 15, l4 = lane >> 4;
    int pos0 = blockIdx.x * 64;

    for (int u = tid; u < 1024; u += 256) {
        int w = u >> 4, u16 = u & 15;
        *(f16x8*)(&lsT[w][u16 * 8]) =
            *(const f16x8*)(s16 + (long long)(pos0 + w) * 128 + u16 * 8);
    }
    __syncthreads();

    f32x4 acc[7];
    {
        f32x4 z = {0.f, 0.f, 0.f, 0.f};
        #pragma unroll
        for (int mt = 0; mt < 7; mt++) acc[mt] = z;
    }
    mfma_tile(w3h, lsT, l15, l4, wv, acc);

    float mu, inv; stats_from(S0, &mu, &inv);
    long long posw = pos0 + wv * 16 + l15;
    double s = 0, q = 0;
    #pragma unroll
    for (int mt = 0; mt < 7; mt++) {
        int ob = mt * 16 + l4 * 4;
        float4 b3 = *(const float4*)(b3e + ob);
        float4 g4 = *(const float4*)(n1g + ob);
        float4 n4 = *(const float4*)(n1b + ob);
        const float* b3p = (const float*)&b3;
        const float* g4p = (const float*)&g4;
        const float* n4p = (const float*)&n4;
        #pragma unroll
        for (int r = 0; r < 4; r++) {
            int o = ob + r;
            float y  = acc[mt][r] + b3p[r];
            float xv = x[(long long)o * NPOS + posw];
            float sc = inv * g4p[r];
            float h0 = xv * sc + (n4p[r] - mu * sc);
            float v  = xv + y + h0;
            x1[(long long)o * NPOS + posw] = v;
            s += (double)v; q += (double)v * v;
        }
    }
    block_reduce2(s, q, S3);
}

// ---- K10: out = x1 + fc2(gelu(fc1'(x1))), via f16 MFMA, in place on x1 buffer ----
__global__ void __launch_bounds__(256, 2)
k_mlp(float* __restrict__ x1out, const _Float16* __restrict__ fc1h,
      const float* __restrict__ b1m, const _Float16* __restrict__ fc2h,
      const float* __restrict__ fc2b) {
    __shared__ __align__(16) _Float16 lxT[64][136];
    __shared__ __align__(16) _Float16 GT[64][456];
    int tid  = threadIdx.x;
    int lane = tid & 63;
    int wv   = tid >> 6;
    int l15  = lane & 15;
    int l4   = lane >> 4;            // 0..3
    int pos0 = blockIdx.x * 64;

    // ---- stage 0: load + transpose + f16-convert x1 tile ----
    {
        int c0 = tid >> 4;           // 0..15
        int q  = tid & 15;           // float4 group within row
        #pragma unroll
        for (int p = 0; p < 7; p++) {
            int c = p * 16 + c0;
            float4 v = *(const float4*)(x1out + (long long)c * NPOS + pos0 + q * 4);
            lxT[q * 4 + 0][c] = (_Float16)v.x;
            lxT[q * 4 + 1][c] = (_Float16)v.y;
            lxT[q * 4 + 2][c] = (_Float16)v.z;
            lxT[q * 4 + 3][c] = (_Float16)v.w;
        }
        for (int i = tid; i < 64 * 16; i += 256) {
            lxT[i >> 4][112 + (i & 15)] = (_Float16)0.f;
        }
    }
    __syncthreads();

    // ---- stage 1: H = fc1h(448x128) * X(128x64); this wave: hid rows [hb, hb+112) ----
    int hb = wv * 112;
    f32x4 acc1[7][4];
    {
        f32x4 z = {0.f, 0.f, 0.f, 0.f};
        #pragma unroll
        for (int mt = 0; mt < 7; mt++)
            #pragma unroll
            for (int nt = 0; nt < 4; nt++) acc1[mt][nt] = z;
    }
    #pragma unroll
    for (int kk = 0; kk < 4; kk++) {
        f16x8 a[7];
        #pragma unroll
        for (int mt = 0; mt < 7; mt++)
            a[mt] = *(const f16x8*)(fc1h + (hb + mt * 16 + l15) * 128 + kk * 32 + l4 * 8);
        #pragma unroll
        for (int nt = 0; nt < 4; nt++) {
            f16x8 b = *(const f16x8*)(&lxT[nt * 16 + l15][kk * 32 + l4 * 8]);
            #pragma unroll
            for (int mt = 0; mt < 7; mt++)
                acc1[mt][nt] = __builtin_amdgcn_mfma_f32_16x16x32_f16(a[mt], b, acc1[mt][nt], 0, 0, 0);
        }
    }
    #pragma unroll
    for (int mt = 0; mt < 7; mt++) {
        int hbase = hb + mt * 16 + l4 * 4;
        float4 bias = *(const float4*)(b1m + hbase);
        #pragma unroll
        for (int nt = 0; nt < 4; nt++) {
            f16x4 g4;
            g4[0] = (_Float16)gelu_f(acc1[mt][nt][0] + bias.x);
            g4[1] = (_Float16)gelu_f(acc1[mt][nt][1] + bias.y);
            g4[2] = (_Float16)gelu_f(acc1[mt][nt][2] + bias.z);
            g4[3] = (_Float16)gelu_f(acc1[mt][nt][3] + bias.w);
            *(f16x4*)(&GT[nt * 16 + l15][hbase]) = g4;
        }
    }
    __syncthreads();

    // ---- stage 2: M = fc2h(112x448) * G(448x16); this wave: pos [wv*16, wv*16+16) ----
    int pw = wv * 16 + l15;
    f32x4 acc2[7];
    {
        f32x4 z = {0.f, 0.f, 0.f, 0.f};
        #pragma unroll
        for (int mt = 0; mt < 7; mt++) acc2[mt] = z;
    }
    #pragma unroll 2
    for (int kk = 0; kk < 14; kk++) {
        f16x8 b = *(const f16x8*)(&GT[pw][kk * 32 + l4 * 8]);
        #pragma unroll
        for (int mt = 0; mt < 7; mt++) {
            f16x8 a = *(const f16x8*)(fc2h + (mt * 16 + l15) * 448 + kk * 32 + l4 * 8);
            acc2[mt] = __builtin_amdgcn_mfma_f32_16x16x32_f16(a, b, acc2[mt], 0, 0, 0);
        }
    }
    long long gp = pos0 + pw;
    #pragma unroll
    for (int mt = 0; mt < 7; mt++) {
        int ob = mt * 16 + l4 * 4;
        float4 b2 = *(const float4*)(fc2b + ob);
        float bb[4] = {b2.x, b2.y, b2.z, b2.w};
        #pragma unroll
        for (int r = 0; r < 4; r++) {
            long long idx = (long long)(ob + r) * NPOS + gp;
            x1out[idx] = x1out[idx] + acc2[mt][r] + bb[r];
        }
    }
}

extern "C" void kernel_launch(void* const* d_in, const int* in_sizes, int n_in,
                              void* d_out, int out_size, void* d_ws, size_t ws_size,
                              hipStream_t stream) {
    const float* x       = (const float*)d_in[0];
    const float* conv1_w = (const float*)d_in[1];
    const float* conv1_b = (const float*)d_in[2];
    const float* conv2d_w= (const float*)d_in[3];
    const float* conv2d_b= (const float*)d_in[4];
    const float* conv2h_w= (const float*)d_in[5];
    const float* conv2h_b= (const float*)d_in[6];
    const float* conv2w_w= (const float*)d_in[7];
    const float* conv2w_b= (const float*)d_in[8];
    const float* conv3_w = (const float*)d_in[9];
    const float* conv3_b = (const float*)d_in[10];
    const float* fc1_w   = (const float*)d_in[11];
    const float* fc1_b   = (const float*)d_in[12];
    const float* fc2_w   = (const float*)d_in[13];
    const float* fc2_b   = (const float*)d_in[14];
    const float* n1_g    = (const float*)d_in[15];
    const float* n1_b    = (const float*)d_in[16];
    const float* na1_g   = (const float*)d_in[17];
    const float* na1_b   = (const float*)d_in[18];
    const float* na2_g   = (const float*)d_in[19];
    const float* na2_b   = (const float*)d_in[20];
    const float* n2_g    = (const float*)d_in[21];
    const float* n2_b    = (const float*)d_in[22];

    char* ws = (char*)d_ws;
    double* S = (double*)ws;                 // S0=S, S1=S+2, S2=S+4, S3=S+6
    float* b1e = (float*)(ws + 512);         // 112
    float* b3e = b1e + 112;                  // 112
    float* b1m = b3e + 112;                  // 448
    // f16 weights, 16B-aligned (starts at ws+3200)
    _Float16* w1h  = (_Float16*)(ws + 3200); // 112*128
    _Float16* w3h  = w1h  + 112 * 128;
    _Float16* w2dh = w3h  + 112 * 128;
    _Float16* w2hh = w2dh + 112 * 128;
    _Float16* w2wh = w2hh + 112 * 128;
    _Float16* fc1h = w2wh + 112 * 128;       // 448*128
    _Float16* fc2h = fc1h + 448 * 128;       // 112*448  (ends < 1 MB)
    float* bufA = (float*)(ws + (1 << 20));  // big scratch: t16 then s16 (64 MB each)
    _Float16* t16 = (_Float16*)bufA;
    _Float16* s16 = (_Float16*)bufA;         // t16 dead when s16 written
    float* out  = (float*)d_out;             // a16, then x1 (f32)
    _Float16* a16 = (_Float16*)out;

    hipMemsetAsync(S, 0, 8 * sizeof(double), stream);
    k_cast<<<448, 128, 0, stream>>>(conv2d_w, conv2h_w, conv2w_w, fc2_w,
                                    w2dh, w2hh, w2wh, fc2h);
    k_reduce<<<1024, 256, 0, stream>>>(x, S);
    k_fold<<<112, 128, 0, stream>>>(S, conv1_w, conv1_b, n1_g, n1_b, w1h, b1e);
    k_conv1<<<4096, 256, 0, stream>>>(x, w1h, b1e, t16, S + 2);
    k_act<<<16384, 256, 0, stream>>>(t16, a16, S + 2, na1_g, na1_b);
    k_shift<<<4096, 256, 0, stream>>>(a16, w2dh, conv2d_b, w2hh, conv2h_b,
                                      w2wh, conv2w_b, s16, S + 4);
    k_fold<<<112, 128, 0, stream>>>(S + 4, conv3_w, conv3_b, na2_g, na2_b, w3h, b3e);
    k_comb<<<4096, 256, 0, stream>>>(s16, x, w3h, b3e, S, n1_g, n1_b, out, S + 6);
    k_fold<<<448, 128, 0, stream>>>(S + 6, fc1_w, fc1_b, n2_g, n2_b, fc1h, b1m);
    k_mlp<<<4096, 256, 0, stream>>>(out, fc1h, b1m, fc2h, fc2_b);
}

// Round 3
// 1126.046 us; speedup vs baseline: 1.8807x; 1.0670x over previous
//
#include <hip/hip_runtime.h>
#include <math.h>

static constexpr int CH   = 112;
static constexpr int HID  = 448;
static constexpr int NPOS = 64 * 64 * 64;            // 262144 = 2^18
static constexpr long long NELEM = (long long)CH * NPOS; // 29360128

typedef _Float16 f16x8 __attribute__((ext_vector_type(8)));
typedef _Float16 f16x4 __attribute__((ext_vector_type(4)));
typedef float    f32x4 __attribute__((ext_vector_type(4)));

// exact-erf GELU via Abramowitz–Stegun 7.1.26 (|err_erf| < 1.5e-7, branchless)
__device__ __forceinline__ float gelu_f(float x) {
    float ax = fabsf(x) * 0.70710678118654752f;     // |x|/sqrt(2)
    float t  = __builtin_amdgcn_rcpf(1.0f + 0.3275911f * ax);
    float p  = t * (0.254829592f + t * (-0.284496736f + t * (1.421413741f +
               t * (-1.453152027f + t * 1.061405429f))));
    float e  = exp2f(-1.4426950408889634f * ax * ax);
    float er = 1.0f - p * e;                        // erf(|x|/sqrt2)
    er = (x < 0.f) ? -er : er;
    return 0.5f * x * (1.0f + er);
}

__device__ __forceinline__ void stats_from(const double* __restrict__ S, float* mu, float* inv) {
    double m = S[0] / (double)NELEM;
    double v = S[1] / (double)NELEM - m * m;
    *mu  = (float)m;
    *inv = (float)(1.0 / sqrt(v + 1e-5));
}

__device__ __forceinline__ void block_reduce2(double s, double q, double* __restrict__ out) {
    #pragma unroll
    for (int off = 32; off > 0; off >>= 1) {
        s += __shfl_down(s, off, 64);
        q += __shfl_down(q, off, 64);
    }
    __shared__ double red[16];
    int lane = threadIdx.x & 63, wv = threadIdx.x >> 6;
    int nw = blockDim.x >> 6;
    if (lane == 0) { red[wv] = s; red[wv + 8] = q; }
    __syncthreads();
    if (threadIdx.x == 0) {
        double S = 0, Q = 0;
        for (int i = 0; i < nw; i++) { S += red[i]; Q += red[i + 8]; }
        atomicAdd(out, S);
        atomicAdd(out + 1, Q);
    }
}

// 7m x 1n(per-wave) x 4k MFMA tile: A = w[o][128] f16, B = lsT[pos][c]
__device__ __forceinline__ void mfma_tile(const _Float16* __restrict__ w,
                                          const _Float16 (*lsT)[136],
                                          int l15, int l4, int wv, f32x4 acc[7]) {
    #pragma unroll
    for (int kk = 0; kk < 4; kk++) {
        f16x8 b = *(const f16x8*)(&lsT[wv * 16 + l15][kk * 32 + l4 * 8]);
        #pragma unroll
        for (int mt = 0; mt < 7; mt++) {
            f16x8 a = *(const f16x8*)(w + (mt * 16 + l15) * 128 + kk * 32 + l4 * 8);
            acc[mt] = __builtin_amdgcn_mfma_f32_16x16x32_f16(a, b, acc[mt], 0, 0, 0);
        }
    }
}

__device__ __forceinline__ void accum_gelu(f32x4 tot[7], const f32x4 acc[7],
                                           const float* __restrict__ b, int l4) {
    #pragma unroll
    for (int mt = 0; mt < 7; mt++) {
        float4 bb = *(const float4*)(b + mt * 16 + l4 * 4);
        tot[mt][0] += gelu_f(acc[mt][0] + bb.x);
        tot[mt][1] += gelu_f(acc[mt][1] + bb.y);
        tot[mt][2] += gelu_f(acc[mt][2] + bb.z);
        tot[mt][3] += gelu_f(acc[mt][3] + bb.w);
    }
}

// ---- K1: reduce x -> S0 ----
__global__ void k_reduce(const float* __restrict__ x, double* __restrict__ S) {
    long long i0 = (long long)blockIdx.x * blockDim.x + threadIdx.x;
    long long stride = (long long)gridDim.x * blockDim.x;
    const float4* x4 = (const float4*)x;
    long long n4 = NELEM / 4;
    double s = 0, q = 0;
    for (long long i = i0; i < n4; i += stride) {
        float4 v = x4[i];
        s += (double)v.x + (double)v.y + (double)v.z + (double)v.w;
        q += (double)v.x * v.x + (double)v.y * v.y + (double)v.z * v.z + (double)v.w * v.w;
    }
    block_reduce2(s, q, S);
}

// ---- generic fold: gn(stats,g,bta) into conv/fc weights; writes f16 [o][128] K-padded, beff[o]
__global__ void k_fold(const double* __restrict__ S, const float* __restrict__ w,
                       const float* __restrict__ b, const float* __restrict__ g,
                       const float* __restrict__ bta,
                       _Float16* __restrict__ w16, float* __restrict__ beff) {
    int o = blockIdx.x;
    float mu, inv; stats_from(S, &mu, &inv);
    float partial = 0.f;
    for (int c = threadIdx.x; c < 128; c += blockDim.x) {
        float wv_ = 0.f, contrib = 0.f;
        if (c < CH) {
            float sc = inv * g[c];
            float sh = bta[c] - mu * sc;
            float w0 = w[o * CH + c];
            wv_ = w0 * sc;
            contrib = w0 * sh;
        }
        w16[o * 128 + c] = (_Float16)wv_;
        partial += contrib;
    }
    #pragma unroll
    for (int off = 32; off > 0; off >>= 1) partial += __shfl_down(partial, off, 64);
    __shared__ float rp[2];
    int lane = threadIdx.x & 63, wv_ = threadIdx.x >> 6;
    if (lane == 0) rp[wv_] = partial;
    __syncthreads();
    if (threadIdx.x == 0) beff[o] = b[o] + rp[0] + rp[1];
}

// ---- casts (no stats deps): w2{d,h,w} -> f16 [o][128] K-padded; fc2 -> f16 same layout
__global__ void k_cast(const float* __restrict__ w2d, const float* __restrict__ w2h,
                       const float* __restrict__ w2w, const float* __restrict__ fc2w,
                       _Float16* __restrict__ w2dh, _Float16* __restrict__ w2hh,
                       _Float16* __restrict__ w2wh, _Float16* __restrict__ fc2h) {
    int b = blockIdx.x;
    if (b < CH) {
        for (int c = threadIdx.x; c < 128; c += blockDim.x) {
            float vd = 0.f, vh = 0.f, vw = 0.f;
            if (c < CH) { vd = w2d[b * CH + c]; vh = w2h[b * CH + c]; vw = w2w[b * CH + c]; }
            w2dh[b * 128 + c] = (_Float16)vd;
            w2hh[b * 128 + c] = (_Float16)vh;
            w2wh[b * 128 + c] = (_Float16)vw;
        }
    }
    for (int i = threadIdx.x; i < CH; i += blockDim.x)
        fc2h[b * CH + i] = (_Float16)fc2w[b * CH + i];
}

// ---- K3: t16[pos][128] = conv1'(x) (gn folded) f16, + stats of t (pre-round f32) -> S1 ----
__global__ void __launch_bounds__(256, 2)
k_conv1(const float* __restrict__ x, const _Float16* __restrict__ w1h,
        const float* __restrict__ b1e, _Float16* __restrict__ t16, double* __restrict__ S1) {
    __shared__ __align__(16) _Float16 lxT[64][136];
    int tid = threadIdx.x, lane = tid & 63, wv = tid >> 6, l15 = lane & 15, l4 = lane >> 4;
    int pos0 = blockIdx.x * 64;

    // stage: x chan-major f32 -> lxT[pos][c] f16 (transpose)
    {
        int c0 = tid >> 4, q = tid & 15;
        #pragma unroll
        for (int p = 0; p < 7; p++) {
            int c = p * 16 + c0;
            float4 v = *(const float4*)(x + (long long)c * NPOS + pos0 + q * 4);
            lxT[q * 4 + 0][c] = (_Float16)v.x;
            lxT[q * 4 + 1][c] = (_Float16)v.y;
            lxT[q * 4 + 2][c] = (_Float16)v.z;
            lxT[q * 4 + 3][c] = (_Float16)v.w;
        }
        for (int i = tid; i < 64 * 16; i += 256) lxT[i >> 4][112 + (i & 15)] = (_Float16)0.f;
    }
    __syncthreads();

    f32x4 acc[7];
    {
        f32x4 z = {0.f, 0.f, 0.f, 0.f};
        #pragma unroll
        for (int mt = 0; mt < 7; mt++) acc[mt] = z;
    }
    mfma_tile(w1h, lxT, l15, l4, wv, acc);

    long long posw = pos0 + wv * 16 + l15;
    double s = 0, q = 0;
    #pragma unroll
    for (int mt = 0; mt < 7; mt++) {
        int ob = mt * 16 + l4 * 4;
        float4 bb = *(const float4*)(b1e + ob);
        const float* bp = (const float*)&bb;
        f16x4 o4;
        #pragma unroll
        for (int r = 0; r < 4; r++) {
            float tv = acc[mt][r] + bp[r];
            o4[r] = (_Float16)tv;
            s += (double)tv; q += (double)tv * tv;
        }
        *(f16x4*)(t16 + posw * 128 + ob) = o4;
    }
    {   // zero K-pad columns so downstream fragments read zeros
        f16x4 z4; z4[0] = z4[1] = z4[2] = z4[3] = (_Float16)0.f;
        *(f16x4*)(t16 + posw * 128 + 112 + l4 * 4) = z4;
    }
    block_reduce2(s, q, S1);
}

// ---- K5: a16 = gelu(gn_affine(t16)), both [pos][128] f16 ----
__global__ void k_act(const _Float16* __restrict__ t16, _Float16* __restrict__ a16,
                      const double* __restrict__ S1, const float* __restrict__ g,
                      const float* __restrict__ bta) {
    float mu, inv; stats_from(S1, &mu, &inv);
    long long i8 = (long long)blockIdx.x * blockDim.x + threadIdx.x; // f16x8 unit
    int c = (int)((i8 * 8) & 127);
    f16x8 r;
    if (c < 112) {
        f16x8 v = *(const f16x8*)(t16 + i8 * 8);
        float4 g0 = *(const float4*)(g + c);
        float4 g1 = *(const float4*)(g + c + 4);
        float4 b0 = *(const float4*)(bta + c);
        float4 b1 = *(const float4*)(bta + c + 4);
        const float* gp0 = (const float*)&g0; const float* gp1 = (const float*)&g1;
        const float* bp0 = (const float*)&b0; const float* bp1 = (const float*)&b1;
        #pragma unroll
        for (int j = 0; j < 4; j++) {
            float sc = inv * gp0[j], sh = bp0[j] - mu * sc;
            r[j] = (_Float16)gelu_f((float)v[j] * sc + sh);
        }
        #pragma unroll
        for (int j = 0; j < 4; j++) {
            float sc = inv * gp1[j], sh = bp1[j] - mu * sc;
            r[4 + j] = (_Float16)gelu_f((float)v[4 + j] * sc + sh);
        }
    } else {
        #pragma unroll
        for (int j = 0; j < 8; j++) r[j] = (_Float16)0.f;
    }
    *(f16x8*)(a16 + i8 * 8) = r;
}

// ---- K6: s16 = sum of 3 shifted-conv-gelu branches (f16 MFMA), + stats -> S2 ----
__global__ void __launch_bounds__(256, 2)
k_shift(const _Float16* __restrict__ a16,
        const _Float16* __restrict__ w2dh, const float* __restrict__ b2d,
        const _Float16* __restrict__ w2hh, const float* __restrict__ b2h,
        const _Float16* __restrict__ w2wh, const float* __restrict__ b2w,
        _Float16* __restrict__ s16, double* __restrict__ S2) {
    __shared__ __align__(16) _Float16 lsT[64][136];
    int tid = threadIdx.x, lane = tid & 63, wv = tid >> 6, l15 = lane & 15, l4 = lane >> 4;
    int d = blockIdx.x >> 6, h = blockIdx.x & 63;

    f32x4 tot[7], acc[7];
    {
        f32x4 z = {0.f, 0.f, 0.f, 0.f};
        #pragma unroll
        for (int mt = 0; mt < 7; mt++) tot[mt] = z;
    }
    f16x8 z8;
    #pragma unroll
    for (int j = 0; j < 8; j++) z8[j] = (_Float16)0.f;

    // ====== branch D: src = a[c, d - sft_p, h, w] ======
    for (int u = tid; u < 1024; u += 256) {
        int w = u >> 4, u16 = u & 15;
        f16x8 v = z8;
        if (u16 < 14) {
            int p = u16 >> 1;                 // channel group 0..6
            int dd = d - (p - 3);
            if ((unsigned)dd < 64u)
                v = *(const f16x8*)(a16 + (long long)(dd * 4096 + h * 64 + w) * 128 + u16 * 8);
        }
        *(f16x8*)(&lsT[w][u16 * 8]) = v;
    }
    __syncthreads();
    {
        f32x4 z = {0.f, 0.f, 0.f, 0.f};
        #pragma unroll
        for (int mt = 0; mt < 7; mt++) acc[mt] = z;
    }
    mfma_tile(w2dh, lsT, l15, l4, wv, acc);
    accum_gelu(tot, acc, b2d, l4);
    __syncthreads();

    // ====== branch H: src = a[c, d-3, h - p, w-3] ======
    {
        int dd = d - 3;
        bool dok = (unsigned)dd < 64u;
        for (int u = tid; u < 1024; u += 256) {
            int w = u >> 4, u16 = u & 15;
            f16x8 v = z8;
            if (u16 < 14) {
                int p = u16 >> 1;
                int hh = h - p;               // h - 3 - (p-3)
                int ww = w - 3;
                if (dok && (unsigned)hh < 64u && ww >= 0)
                    v = *(const f16x8*)(a16 + (long long)(dd * 4096 + hh * 64 + ww) * 128 + u16 * 8);
            }
            *(f16x8*)(&lsT[w][u16 * 8]) = v;
        }
    }
    __syncthreads();
    {
        f32x4 z = {0.f, 0.f, 0.f, 0.f};
        #pragma unroll
        for (int mt = 0; mt < 7; mt++) acc[mt] = z;
    }
    mfma_tile(w2hh, lsT, l15, l4, wv, acc);
    accum_gelu(tot, acc, b2h, l4);
    __syncthreads();

    // ====== branch W: src = a[c, d-6, h-6, w - 3 - p] ======
    {
        int dd = d - 6, hh = h - 6;
        bool ok = ((unsigned)dd < 64u) && ((unsigned)hh < 64u);
        for (int u = tid; u < 1024; u += 256) {
            int w = u >> 4, u16 = u & 15;
            f16x8 v = z8;
            if (ok && u16 < 14) {
                int p = u16 >> 1;
                int ww = w - 3 - p;           // w - 6 - (p-3)
                if ((unsigned)ww < 64u)
                    v = *(const f16x8*)(a16 + (long long)(dd * 4096 + hh * 64 + ww) * 128 + u16 * 8);
            }
            *(f16x8*)(&lsT[w][u16 * 8]) = v;
        }
    }
    __syncthreads();
    {
        f32x4 z = {0.f, 0.f, 0.f, 0.f};
        #pragma unroll
        for (int mt = 0; mt < 7; mt++) acc[mt] = z;
    }
    mfma_tile(w2wh, lsT, l15, l4, wv, acc);
    accum_gelu(tot, acc, b2w, l4);

    // epilogue: s16 [pos][128] f16, stats from f32
    long long posw = d * 4096 + h * 64 + wv * 16 + l15;
    double s = 0, q = 0;
    #pragma unroll
    for (int mt = 0; mt < 7; mt++) {
        f16x4 o4;
        #pragma unroll
        for (int r = 0; r < 4; r++) {
            float sv = tot[mt][r];
            o4[r] = (_Float16)sv;
            s += (double)sv; q += (double)sv * sv;
        }
        *(f16x4*)(s16 + posw * 128 + mt * 16 + l4 * 4) = o4;
    }
    {
        f16x4 z4; z4[0] = z4[1] = z4[2] = z4[3] = (_Float16)0.f;
        *(f16x4*)(s16 + posw * 128 + 112 + l4 * 4) = z4;
    }
    block_reduce2(s, q, S2);
}

// ---- K8: x1 = x + conv3'(s16) + h0(x), + stats -> S3; also emits x1h f16 [pos][128]
//      x1h aliases s16 (in-place, per-block-private footprint: each block reads its own
//      pos-tile into LDS before overwriting the same rows; pad cols 112..127 stay zero).
__global__ void __launch_bounds__(256, 2)
k_comb(const _Float16* s16, const float* __restrict__ x,
       const _Float16* __restrict__ w3h, const float* __restrict__ b3e,
       const double* __restrict__ S0, const float* __restrict__ n1g,
       const float* __restrict__ n1b, float* __restrict__ x1,
       _Float16* x1h, double* __restrict__ S3) {
    __shared__ __align__(16) _Float16 lsT[64][136];
    int tid = threadIdx.x, lane = tid & 63, wv = tid >> 6, l15 = lane & 15, l4 = lane >> 4;
    int pos0 = blockIdx.x * 64;

    for (int u = tid; u < 1024; u += 256) {
        int w = u >> 4, u16 = u & 15;
        *(f16x8*)(&lsT[w][u16 * 8]) =
            *(const f16x8*)(s16 + (long long)(pos0 + w) * 128 + u16 * 8);
    }
    __syncthreads();

    f32x4 acc[7];
    {
        f32x4 z = {0.f, 0.f, 0.f, 0.f};
        #pragma unroll
        for (int mt = 0; mt < 7; mt++) acc[mt] = z;
    }
    mfma_tile(w3h, lsT, l15, l4, wv, acc);

    float mu, inv; stats_from(S0, &mu, &inv);
    long long posw = pos0 + wv * 16 + l15;
    double s = 0, q = 0;
    #pragma unroll
    for (int mt = 0; mt < 7; mt++) {
        int ob = mt * 16 + l4 * 4;
        float4 b3 = *(const float4*)(b3e + ob);
        float4 g4 = *(const float4*)(n1g + ob);
        float4 n4 = *(const float4*)(n1b + ob);
        const float* b3p = (const float*)&b3;
        const float* g4p = (const float*)&g4;
        const float* n4p = (const float*)&n4;
        f16x4 o4;
        #pragma unroll
        for (int r = 0; r < 4; r++) {
            int o = ob + r;
            float y  = acc[mt][r] + b3p[r];
            float xv = x[(long long)o * NPOS + posw];
            float sc = inv * g4p[r];
            float h0 = xv * sc + (n4p[r] - mu * sc);
            float v  = xv + y + h0;
            x1[(long long)o * NPOS + posw] = v;
            o4[r] = (_Float16)v;
            s += (double)v; q += (double)v * v;
        }
        *(f16x4*)(x1h + posw * 128 + ob) = o4;
    }
    block_reduce2(s, q, S3);
}

// ---- K10: out = x1 + fc2(gelu(fc1'(x1))) via f16 MFMA ----
// x1h [pos][128] f16 input (no transpose). LDS union (29.7 KB): lxT during fc1,
// then GT half-buffer [64][232] for the two 224-wide fc2 K-phases.
__global__ void __launch_bounds__(256, 3)
k_mlp(float* __restrict__ x1out, const _Float16* __restrict__ x1h,
      const _Float16* __restrict__ fc1h, const float* __restrict__ b1m,
      const _Float16* __restrict__ fc2h, const float* __restrict__ fc2b) {
    __shared__ __align__(16) char smem[64 * 232 * 2];
    _Float16 (*lxT)[136] = (_Float16 (*)[136])smem;
    _Float16 (*GT)[232]  = (_Float16 (*)[232])smem;
    int tid = threadIdx.x, lane = tid & 63, wv = tid >> 6, l15 = lane & 15, l4 = lane >> 4;
    int pos0 = blockIdx.x * 64;

    // ---- stage 0: coalesced f16 staging of x1h tile (pads included, zero) ----
    for (int u = tid; u < 1024; u += 256) {
        int w = u >> 4, u16 = u & 15;
        *(f16x8*)(&lxT[w][u16 * 8]) =
            *(const f16x8*)(x1h + (long long)(pos0 + w) * 128 + u16 * 8);
    }
    __syncthreads();

    // ---- stage 1: H = fc1h(448x128) * X(128x64); this wave: hid [wv*112, +112) ----
    int hb = wv * 112;
    f32x4 acc1[7][4];
    {
        f32x4 z = {0.f, 0.f, 0.f, 0.f};
        #pragma unroll
        for (int mt = 0; mt < 7; mt++)
            #pragma unroll
            for (int nt = 0; nt < 4; nt++) acc1[mt][nt] = z;
    }
    #pragma unroll
    for (int kk = 0; kk < 4; kk++) {
        f16x8 a[7];
        #pragma unroll
        for (int mt = 0; mt < 7; mt++)
            a[mt] = *(const f16x8*)(fc1h + (hb + mt * 16 + l15) * 128 + kk * 32 + l4 * 8);
        #pragma unroll
        for (int nt = 0; nt < 4; nt++) {
            f16x8 b = *(const f16x8*)(&lxT[nt * 16 + l15][kk * 32 + l4 * 8]);
            #pragma unroll
            for (int mt = 0; mt < 7; mt++)
                acc1[mt][nt] = __builtin_amdgcn_mfma_f32_16x16x32_f16(a[mt], b, acc1[mt][nt], 0, 0, 0);
        }
    }
    // gelu into f16 registers (G stays resident; no full-448 LDS buffer needed)
    f16x4 g16[7][4];
    #pragma unroll
    for (int mt = 0; mt < 7; mt++) {
        float4 bias = *(const float4*)(b1m + hb + mt * 16 + l4 * 4);
        #pragma unroll
        for (int nt = 0; nt < 4; nt++) {
            g16[mt][nt][0] = (_Float16)gelu_f(acc1[mt][nt][0] + bias.x);
            g16[mt][nt][1] = (_Float16)gelu_f(acc1[mt][nt][1] + bias.y);
            g16[mt][nt][2] = (_Float16)gelu_f(acc1[mt][nt][2] + bias.z);
            g16[mt][nt][3] = (_Float16)gelu_f(acc1[mt][nt][3] + bias.w);
        }
    }
    __syncthreads();   // lxT dead; GT may now overwrite the union

    // ---- stage 2: two K-phases of 224 over GT[64][232] ----
    int pw = wv * 16 + l15;
    f32x4 acc2[7];
    {
        f32x4 z = {0.f, 0.f, 0.f, 0.f};
        #pragma unroll
        for (int mt = 0; mt < 7; mt++) acc2[mt] = z;
    }
    #pragma unroll
    for (int ph = 0; ph < 2; ph++) {
        if ((wv >> 1) == ph) {      // ph0: waves 0,1 publish hid 0..223; ph1: waves 2,3
            int cb = (wv & 1) * 112;
            #pragma unroll
            for (int mt = 0; mt < 7; mt++) {
                int col = cb + mt * 16 + l4 * 4;
                #pragma unroll
                for (int nt = 0; nt < 4; nt++)
                    *(f16x4*)(&GT[nt * 16 + l15][col]) = g16[mt][nt];
            }
        }
        __syncthreads();
        #pragma unroll
        for (int kk = 0; kk < 7; kk++) {
            f16x8 b = *(const f16x8*)(&GT[pw][kk * 32 + l4 * 8]);
            #pragma unroll
            for (int mt = 0; mt < 7; mt++) {
                f16x8 a = *(const f16x8*)(fc2h + (mt * 16 + l15) * 448 + ph * 224 + kk * 32 + l4 * 8);
                acc2[mt] = __builtin_amdgcn_mfma_f32_16x16x32_f16(a, b, acc2[mt], 0, 0, 0);
            }
        }
        if (ph == 0) __syncthreads();   // GT reads done before phase-1 overwrite
    }

    // ---- epilogue: exact f32 residual rmw ----
    long long gp = pos0 + pw;
    #pragma unroll
    for (int mt = 0; mt < 7; mt++) {
        int ob = mt * 16 + l4 * 4;
        float4 b2 = *(const float4*)(fc2b + ob);
        float bb[4] = {b2.x, b2.y, b2.z, b2.w};
        #pragma unroll
        for (int r = 0; r < 4; r++) {
            long long idx = (long long)(ob + r) * NPOS + gp;
            x1out[idx] = x1out[idx] + acc2[mt][r] + bb[r];
        }
    }
}

extern "C" void kernel_launch(void* const* d_in, const int* in_sizes, int n_in,
                              void* d_out, int out_size, void* d_ws, size_t ws_size,
                              hipStream_t stream) {
    const float* x       = (const float*)d_in[0];
    const float* conv1_w = (const float*)d_in[1];
    const float* conv1_b = (const float*)d_in[2];
    const float* conv2d_w= (const float*)d_in[3];
    const float* conv2d_b= (const float*)d_in[4];
    const float* conv2h_w= (const float*)d_in[5];
    const float* conv2h_b= (const float*)d_in[6];
    const float* conv2w_w= (const float*)d_in[7];
    const float* conv2w_b= (const float*)d_in[8];
    const float* conv3_w = (const float*)d_in[9];
    const float* conv3_b = (const float*)d_in[10];
    const float* fc1_w   = (const float*)d_in[11];
    const float* fc1_b   = (const float*)d_in[12];
    const float* fc2_w   = (const float*)d_in[13];
    const float* fc2_b   = (const float*)d_in[14];
    const float* n1_g    = (const float*)d_in[15];
    const float* n1_b    = (const float*)d_in[16];
    const float* na1_g   = (const float*)d_in[17];
    const float* na1_b   = (const float*)d_in[18];
    const float* na2_g   = (const float*)d_in[19];
    const float* na2_b   = (const float*)d_in[20];
    const float* n2_g    = (const float*)d_in[21];
    const float* n2_b    = (const float*)d_in[22];

    char* ws = (char*)d_ws;
    double* S = (double*)ws;                 // S0=S, S1=S+2, S2=S+4, S3=S+6
    float* b1e = (float*)(ws + 512);         // 112
    float* b3e = b1e + 112;                  // 112
    float* b1m = b3e + 112;                  // 448
    _Float16* w1h  = (_Float16*)(ws + 3200); // 112*128
    _Float16* w3h  = w1h  + 112 * 128;
    _Float16* w2dh = w3h  + 112 * 128;
    _Float16* w2hh = w2dh + 112 * 128;
    _Float16* w2wh = w2hh + 112 * 128;
    _Float16* fc1h = w2wh + 112 * 128;       // 448*128
    _Float16* fc2h = fc1h + 448 * 128;       // 112*448  (ends < 1 MB)
    float* bufA = (float*)(ws + (1 << 20));  // big scratch: t16, then s16/x1h (67 MB)
    _Float16* t16 = (_Float16*)bufA;
    _Float16* s16 = (_Float16*)bufA;         // t16 dead when s16 written
    _Float16* x1h = (_Float16*)bufA;         // s16 consumed per-block before overwrite
    float* out  = (float*)d_out;             // a16, then x1 (f32)
    _Float16* a16 = (_Float16*)out;

    hipMemsetAsync(S, 0, 8 * sizeof(double), stream);
    k_cast<<<448, 128, 0, stream>>>(conv2d_w, conv2h_w, conv2w_w, fc2_w,
                                    w2dh, w2hh, w2wh, fc2h);
    k_reduce<<<1024, 256, 0, stream>>>(x, S);
    k_fold<<<112, 128, 0, stream>>>(S, conv1_w, conv1_b, n1_g, n1_b, w1h, b1e);
    k_conv1<<<4096, 256, 0, stream>>>(x, w1h, b1e, t16, S + 2);
    k_act<<<16384, 256, 0, stream>>>(t16, a16, S + 2, na1_g, na1_b);
    k_shift<<<4096, 256, 0, stream>>>(a16, w2dh, conv2d_b, w2hh, conv2h_b,
                                      w2wh, conv2w_b, s16, S + 4);
    k_fold<<<112, 128, 0, stream>>>(S + 4, conv3_w, conv3_b, na2_g, na2_b, w3h, b3e);
    k_comb<<<4096, 256, 0, stream>>>(s16, x, w3h, b3e, S, n1_g, n1_b, out, x1h, S + 6);
    k_fold<<<448, 128, 0, stream>>>(S + 6, fc1_w, fc1_b, n2_g, n2_b, fc1h, b1m);
    k_mlp<<<4096, 256, 0, stream>>>(out, x1h, fc1h, b1m, fc2h, fc2_b);
}